// Round 2
// baseline (276.498 us; speedup 1.0000x reference)
//
#include <hip/hip_runtime.h>

#define NT 512
#define MT 32   // rows per block

typedef __attribute__((ext_vector_type(8))) short short8;
typedef __attribute__((ext_vector_type(4))) float f32x4;
typedef __attribute__((ext_vector_type(4))) unsigned short u16x4;

__device__ __forceinline__ unsigned short f2bf(float f) {
  unsigned int u = __builtin_bit_cast(unsigned int, f);
  u += 0x7fffu + ((u >> 16) & 1u);
  return (unsigned short)(u >> 16);
}

// Convert Wq (512x512), Wk (512x768), Wv (512x768) f32 -> bf16 in workspace.
// Layout kept row-major [out_ch][k] — exactly the B^T (N,K) layout MFMA wants.
__global__ void cvt_weights(const float* __restrict__ wq,
                            const float* __restrict__ wk,
                            const float* __restrict__ wv,
                            unsigned short* __restrict__ o) {
  int stride = gridDim.x * blockDim.x;
  int i0 = blockIdx.x * blockDim.x + threadIdx.x;
  for (int j = i0; j < 512 * 512; j += stride) o[j] = f2bf(wq[j]);
  for (int j = i0; j < 512 * 768; j += stride) o[262144 + j] = f2bf(wk[j]);
  for (int j = i0; j < 512 * 768; j += stride) o[655360 + j] = f2bf(wv[j]);
}

// One block = 32 rows (b,t). 8 waves; wave id == head id (64 ch each).
// LDS = 48KB -> 2 blocks/CU resident; cross-block overlap hides staging.
__global__ __launch_bounds__(NT, 4)
void fused_xattn(const float* __restrict__ x, const float* __restrict__ xf,
                 const float* __restrict__ nw, const float* __restrict__ nb,
                 const float* __restrict__ tw, const float* __restrict__ tb,
                 const unsigned short* __restrict__ wbf,
                 float* __restrict__ out) {
  __shared__ __attribute__((aligned(16))) char smem[49152];  // 32 rows x 768 bf16
  const int tid   = threadIdx.x;
  const int lane  = tid & 63;
  const int wid   = tid >> 6;          // wave == head
  const int lr    = lane & 15;         // row (A) / col (B,C) within 16-tile
  const int lkb   = (lane >> 4) * 8;   // k-offset within fragment
  const int lrow4 = (lane >> 4) * 4;   // C/D row base

  const long row0 = (long)blockIdx.x * MT;
  float* __restrict__ y1 = out;
  float* __restrict__ y2 = out + 16777216L;

  // ---------------- stage LN(x): 32 rows x 512 -> bf16 LDS (stride 1024B) ----
  for (int r = wid; r < MT; r += 8) {
    const f32x4* rp = (const f32x4*)(x + (row0 + r) * 512);
    f32x4 t0 = rp[lane];
    f32x4 t1 = rp[lane + 64];
    float s  = t0.x + t0.y + t0.z + t0.w + t1.x + t1.y + t1.z + t1.w;
    float s2 = t0.x*t0.x + t0.y*t0.y + t0.z*t0.z + t0.w*t0.w
             + t1.x*t1.x + t1.y*t1.y + t1.z*t1.z + t1.w*t1.w;
    #pragma unroll
    for (int m = 1; m < 64; m <<= 1) { s += __shfl_xor(s, m, 64); s2 += __shfl_xor(s2, m, 64); }
    float mean = s * (1.0f / 512.0f);
    float var  = s2 * (1.0f / 512.0f) - mean * mean;
    float rs   = rsqrtf(var + 1e-5f);
    const f32x4* g4 = (const f32x4*)nw;
    const f32x4* b4 = (const f32x4*)nb;
    f32x4 g0 = g4[lane], g1 = g4[lane + 64];
    f32x4 c0 = b4[lane], c1 = b4[lane + 64];
    u16x4 o0 = { f2bf((t0.x - mean) * rs * g0.x + c0.x),
                 f2bf((t0.y - mean) * rs * g0.y + c0.y),
                 f2bf((t0.z - mean) * rs * g0.z + c0.z),
                 f2bf((t0.w - mean) * rs * g0.w + c0.w) };
    u16x4 o1 = { f2bf((t1.x - mean) * rs * g1.x + c1.x),
                 f2bf((t1.y - mean) * rs * g1.y + c1.y),
                 f2bf((t1.z - mean) * rs * g1.z + c1.z),
                 f2bf((t1.w - mean) * rs * g1.w + c1.w) };
    const int base = r * 1024, sw = (r & 7) << 4;
    *(u16x4*)(smem + ((base +       lane * 8) ^ sw)) = o0;
    *(u16x4*)(smem + ((base + 512 + lane * 8) ^ sw)) = o1;
  }
  __syncthreads();

  // ---------------- q GEMM: K=512 --------------------------------------------
  f32x4 qa[2][4] = {};
  {
    const unsigned short* wq = wbf;
    for (int kk = 0; kk < 512; kk += 32) {
      short8 a[2];
      #pragma unroll
      for (int m = 0; m < 2; ++m) {
        int row = m * 16 + lr;
        int off = (row * 1024 + (kk + lkb) * 2) ^ ((row & 7) << 4);
        a[m] = *(const short8*)(smem + off);
      }
      #pragma unroll
      for (int n = 0; n < 4; ++n) {
        short8 b = *(const short8*)(wq + (size_t)(wid * 64 + n * 16 + lr) * 512 + kk + lkb);
        #pragma unroll
        for (int m = 0; m < 2; ++m)
          qa[m][n] = __builtin_amdgcn_mfma_f32_16x16x32_bf16(a[m], b, qa[m][n], 0, 0, 0);
      }
    }
  }
  __syncthreads();

  // ---------------- stage LN(xf): 32 rows x 768 -> bf16 LDS (stride 1536B) ---
  for (int r = wid; r < MT; r += 8) {
    const f32x4* rp = (const f32x4*)(xf + (row0 + r) * 768);
    f32x4 t0 = rp[lane], t1 = rp[lane + 64], t2 = rp[lane + 128];
    float s  = t0.x + t0.y + t0.z + t0.w + t1.x + t1.y + t1.z + t1.w
             + t2.x + t2.y + t2.z + t2.w;
    float s2 = t0.x*t0.x + t0.y*t0.y + t0.z*t0.z + t0.w*t0.w
             + t1.x*t1.x + t1.y*t1.y + t1.z*t1.z + t1.w*t1.w
             + t2.x*t2.x + t2.y*t2.y + t2.z*t2.z + t2.w*t2.w;
    #pragma unroll
    for (int m = 1; m < 64; m <<= 1) { s += __shfl_xor(s, m, 64); s2 += __shfl_xor(s2, m, 64); }
    float mean = s * (1.0f / 768.0f);
    float var  = s2 * (1.0f / 768.0f) - mean * mean;
    float rs   = rsqrtf(var + 1e-5f);
    const f32x4* g4 = (const f32x4*)tw;
    const f32x4* b4 = (const f32x4*)tb;
    f32x4 g0 = g4[lane], g1 = g4[lane + 64], g2 = g4[lane + 128];
    f32x4 c0 = b4[lane], c1 = b4[lane + 64], c2 = b4[lane + 128];
    u16x4 o0 = { f2bf((t0.x - mean) * rs * g0.x + c0.x),
                 f2bf((t0.y - mean) * rs * g0.y + c0.y),
                 f2bf((t0.z - mean) * rs * g0.z + c0.z),
                 f2bf((t0.w - mean) * rs * g0.w + c0.w) };
    u16x4 o1 = { f2bf((t1.x - mean) * rs * g1.x + c1.x),
                 f2bf((t1.y - mean) * rs * g1.y + c1.y),
                 f2bf((t1.z - mean) * rs * g1.z + c1.z),
                 f2bf((t1.w - mean) * rs * g1.w + c1.w) };
    u16x4 o2 = { f2bf((t2.x - mean) * rs * g2.x + c2.x),
                 f2bf((t2.y - mean) * rs * g2.y + c2.y),
                 f2bf((t2.z - mean) * rs * g2.z + c2.z),
                 f2bf((t2.w - mean) * rs * g2.w + c2.w) };
    const int base = r * 1536, sw = (r & 7) << 4;
    *(u16x4*)(smem + ((base +        lane * 8) ^ sw)) = o0;
    *(u16x4*)(smem + ((base + 512  + lane * 8) ^ sw)) = o1;
    *(u16x4*)(smem + ((base + 1024 + lane * 8) ^ sw)) = o2;
  }
  __syncthreads();

  // ---------------- k GEMM: K=768 --------------------------------------------
  f32x4 ka[2][4] = {};
  {
    const unsigned short* wk = wbf + 262144;
    for (int kk = 0; kk < 768; kk += 32) {
      short8 a[2];
      #pragma unroll
      for (int m = 0; m < 2; ++m) {
        int row = m * 16 + lr;
        int off = (row * 1536 + (kk + lkb) * 2) ^ ((row & 7) << 4);
        a[m] = *(const short8*)(smem + off);
      }
      #pragma unroll
      for (int n = 0; n < 4; ++n) {
        short8 b = *(const short8*)(wk + (size_t)(wid * 64 + n * 16 + lr) * 768 + kk + lkb);
        #pragma unroll
        for (int m = 0; m < 2; ++m)
          ka[m][n] = __builtin_amdgcn_mfma_f32_16x16x32_bf16(a[m], b, ka[m][n], 0, 0, 0);
      }
    }
  }

  // ---------------- w gate: w[row,h] = (q·k)/8 over the wave's 64 channels ---
  // C/D layout: col = lane&15, row = (lane>>4)*4 + reg  → reduce across the
  // 16 col-lanes with xor masks 1,2,4,8.
  float wgt[2][4];
  #pragma unroll
  for (int m = 0; m < 2; ++m) {
    #pragma unroll
    for (int r = 0; r < 4; ++r) {
      float p = 0.0f;
      #pragma unroll
      for (int n = 0; n < 4; ++n) p += qa[m][n][r] * ka[m][n][r];
      #pragma unroll
      for (int msk = 1; msk < 16; msk <<= 1) p += __shfl_xor(p, msk, 64);
      wgt[m][r] = p * 0.125f;   // 1/sqrt(64)
    }
  }

  // ---------------- y1 = (1-w) * q -------------------------------------------
  #pragma unroll
  for (int m = 0; m < 2; ++m) {
    #pragma unroll
    for (int r = 0; r < 4; ++r) {
      float f = 1.0f - wgt[m][r];
      long grow = row0 + m * 16 + lrow4 + r;
      #pragma unroll
      for (int n = 0; n < 4; ++n) {
        int ch = wid * 64 + n * 16 + lr;
        y1[grow * 512 + ch] = f * qa[m][n][r];
      }
    }
  }

  // ---------------- v GEMM: K=768, then y2 = w * v ----------------------------
  f32x4 va[2][4] = {};
  {
    const unsigned short* wv = wbf + 655360;
    for (int kk = 0; kk < 768; kk += 32) {
      short8 a[2];
      #pragma unroll
      for (int m = 0; m < 2; ++m) {
        int row = m * 16 + lr;
        int off = (row * 1536 + (kk + lkb) * 2) ^ ((row & 7) << 4);
        a[m] = *(const short8*)(smem + off);
      }
      #pragma unroll
      for (int n = 0; n < 4; ++n) {
        short8 b = *(const short8*)(wv + (size_t)(wid * 64 + n * 16 + lr) * 768 + kk + lkb);
        #pragma unroll
        for (int m = 0; m < 2; ++m)
          va[m][n] = __builtin_amdgcn_mfma_f32_16x16x32_bf16(a[m], b, va[m][n], 0, 0, 0);
      }
    }
  }
  #pragma unroll
  for (int m = 0; m < 2; ++m) {
    #pragma unroll
    for (int r = 0; r < 4; ++r) {
      float f = wgt[m][r];
      long grow = row0 + m * 16 + lrow4 + r;
      #pragma unroll
      for (int n = 0; n < 4; ++n) {
        int ch = wid * 64 + n * 16 + lr;
        y2[grow * 512 + ch] = f * va[m][n][r];
      }
    }
  }
}

extern "C" void kernel_launch(void* const* d_in, const int* in_sizes, int n_in,
                              void* d_out, int out_size, void* d_ws, size_t ws_size,
                              hipStream_t stream) {
  const float* x  = (const float*)d_in[0];
  const float* xf = (const float*)d_in[1];
  const float* nw = (const float*)d_in[2];
  const float* nb = (const float*)d_in[3];
  const float* tw = (const float*)d_in[4];
  const float* tb = (const float*)d_in[5];
  const float* wq = (const float*)d_in[6];
  const float* wk = (const float*)d_in[7];
  const float* wv = (const float*)d_in[8];
  unsigned short* wbf = (unsigned short*)d_ws;   // 2 MB bf16 weights

  cvt_weights<<<256, 256, 0, stream>>>(wq, wk, wv, wbf);
  fused_xattn<<<1024, NT, 0, stream>>>(x, xf, nw, nb, tw, tb, wbf, (float*)d_out);
}

// Round 3
// 170.694 us; speedup vs baseline: 1.6198x; 1.6198x over previous
//
#include <hip/hip_runtime.h>

#define NT 512
#define MT 32   // rows per block

typedef __attribute__((ext_vector_type(8))) short short8;
typedef __attribute__((ext_vector_type(4))) float f32x4;
typedef __attribute__((ext_vector_type(4))) unsigned short u16x4;

__device__ __forceinline__ unsigned short f2bf(float f) {
  unsigned int u = __builtin_bit_cast(unsigned int, f);
  u += 0x7fffu + ((u >> 16) & 1u);
  return (unsigned short)(u >> 16);
}

// Repack Wq (512x512), Wk (512x768), Wv (512x768) f32 -> bf16 fragments in
// MFMA operand order: frag[head][kk32][n][lane][8 shorts]. A B-fragment load
// is then lane*16B contiguous -> one coalesced 1KB wave load.
__global__ void cvt_weights(const float* __restrict__ wq,
                            const float* __restrict__ wk,
                            const float* __restrict__ wv,
                            unsigned short* __restrict__ o) {
  int stride = gridDim.x * blockDim.x;
  int i0 = blockIdx.x * blockDim.x + threadIdx.x;
  // q: 8 heads x 16 kk32 x 4 n x 64 lanes = 32768 fragment-lanes
  for (int t = i0; t < 32768; t += stride) {
    int lane = t & 63, n = (t >> 6) & 3, kk32 = (t >> 8) & 15, head = t >> 12;
    int row = head * 64 + n * 16 + (lane & 15);
    int k   = kk32 * 32 + (lane >> 4) * 8;
    const float* s = wq + (size_t)row * 512 + k;
    unsigned short* d = o + (size_t)t * 8;
    #pragma unroll
    for (int e = 0; e < 8; ++e) d[e] = f2bf(s[e]);
  }
  // k: 8 heads x 24 kk32 x 4 n x 64 lanes = 49152 fragment-lanes
  for (int t = i0; t < 49152; t += stride) {
    int lane = t & 63, n = (t >> 6) & 3, rem = t >> 8;
    int kk32 = rem % 24, head = rem / 24;
    int row = head * 64 + n * 16 + (lane & 15);
    int k   = kk32 * 32 + (lane >> 4) * 8;
    const float* s = wk + (size_t)row * 768 + k;
    unsigned short* d = o + 262144 + (size_t)t * 8;
    #pragma unroll
    for (int e = 0; e < 8; ++e) d[e] = f2bf(s[e]);
  }
  // v: same shape as k
  for (int t = i0; t < 49152; t += stride) {
    int lane = t & 63, n = (t >> 6) & 3, rem = t >> 8;
    int kk32 = rem % 24, head = rem / 24;
    int row = head * 64 + n * 16 + (lane & 15);
    int k   = kk32 * 32 + (lane >> 4) * 8;
    const float* s = wv + (size_t)row * 768 + k;
    unsigned short* d = o + 655360 + (size_t)t * 8;
    #pragma unroll
    for (int e = 0; e < 8; ++e) d[e] = f2bf(s[e]);
  }
}

// One block = 32 rows (b,t). 8 waves; wave id == head id (64 ch each).
// LDS = 48KB -> 2 blocks/CU resident; cross-block overlap hides staging.
__global__ __launch_bounds__(NT, 4)
void fused_xattn(const float* __restrict__ x, const float* __restrict__ xf,
                 const float* __restrict__ nw, const float* __restrict__ nb,
                 const float* __restrict__ tw, const float* __restrict__ tb,
                 const unsigned short* __restrict__ wbf,
                 float* __restrict__ out) {
  __shared__ __attribute__((aligned(16))) char smem[49152];  // 32 rows x 768 bf16
  const int tid   = threadIdx.x;
  const int lane  = tid & 63;
  const int wid   = tid >> 6;          // wave == head
  const int lr    = lane & 15;         // row (A) / col (B,C) within 16-tile
  const int lkb   = (lane >> 4) * 8;   // k-offset within fragment
  const int lrow4 = (lane >> 4) * 4;   // C/D row base

  const long row0 = (long)blockIdx.x * MT;
  float* __restrict__ y1 = out;
  float* __restrict__ y2 = out + 16777216L;

  // ---------------- stage LN(x): 32 rows x 512 -> bf16 LDS (stride 1024B) ----
  for (int r = wid; r < MT; r += 8) {
    const f32x4* rp = (const f32x4*)(x + (row0 + r) * 512);
    f32x4 t0 = rp[lane];
    f32x4 t1 = rp[lane + 64];
    float s  = t0.x + t0.y + t0.z + t0.w + t1.x + t1.y + t1.z + t1.w;
    float s2 = t0.x*t0.x + t0.y*t0.y + t0.z*t0.z + t0.w*t0.w
             + t1.x*t1.x + t1.y*t1.y + t1.z*t1.z + t1.w*t1.w;
    #pragma unroll
    for (int m = 1; m < 64; m <<= 1) { s += __shfl_xor(s, m, 64); s2 += __shfl_xor(s2, m, 64); }
    float mean = s * (1.0f / 512.0f);
    float var  = s2 * (1.0f / 512.0f) - mean * mean;
    float rs   = rsqrtf(var + 1e-5f);
    const f32x4* g4 = (const f32x4*)nw;
    const f32x4* b4 = (const f32x4*)nb;
    f32x4 g0 = g4[lane], g1 = g4[lane + 64];
    f32x4 c0 = b4[lane], c1 = b4[lane + 64];
    u16x4 o0 = { f2bf((t0.x - mean) * rs * g0.x + c0.x),
                 f2bf((t0.y - mean) * rs * g0.y + c0.y),
                 f2bf((t0.z - mean) * rs * g0.z + c0.z),
                 f2bf((t0.w - mean) * rs * g0.w + c0.w) };
    u16x4 o1 = { f2bf((t1.x - mean) * rs * g1.x + c1.x),
                 f2bf((t1.y - mean) * rs * g1.y + c1.y),
                 f2bf((t1.z - mean) * rs * g1.z + c1.z),
                 f2bf((t1.w - mean) * rs * g1.w + c1.w) };
    const int base = r * 1024, sw = (r & 7) << 4;
    *(u16x4*)(smem + ((base +       lane * 8) ^ sw)) = o0;
    *(u16x4*)(smem + ((base + 512 + lane * 8) ^ sw)) = o1;
  }
  __syncthreads();

  // ---------------- q GEMM: K=512 --------------------------------------------
  f32x4 qa[2][4] = {};
  {
    const unsigned short* bq = wbf + wid * 32768 + lane * 8;
    for (int kk32 = 0; kk32 < 16; ++kk32) {
      short8 a[2];
      #pragma unroll
      for (int m = 0; m < 2; ++m) {
        int row = m * 16 + lr;
        int off = (row * 1024 + (kk32 * 32 + lkb) * 2) ^ ((row & 7) << 4);
        a[m] = *(const short8*)(smem + off);
      }
      #pragma unroll
      for (int n = 0; n < 4; ++n) {
        short8 b = *(const short8*)(bq + kk32 * 2048 + n * 512);
        #pragma unroll
        for (int m = 0; m < 2; ++m)
          qa[m][n] = __builtin_amdgcn_mfma_f32_16x16x32_bf16(a[m], b, qa[m][n], 0, 0, 0);
      }
    }
  }
  __syncthreads();

  // ---------------- stage LN(xf): 32 rows x 768 -> bf16 LDS (stride 1536B) ---
  for (int r = wid; r < MT; r += 8) {
    const f32x4* rp = (const f32x4*)(xf + (row0 + r) * 768);
    f32x4 t0 = rp[lane], t1 = rp[lane + 64], t2 = rp[lane + 128];
    float s  = t0.x + t0.y + t0.z + t0.w + t1.x + t1.y + t1.z + t1.w
             + t2.x + t2.y + t2.z + t2.w;
    float s2 = t0.x*t0.x + t0.y*t0.y + t0.z*t0.z + t0.w*t0.w
             + t1.x*t1.x + t1.y*t1.y + t1.z*t1.z + t1.w*t1.w
             + t2.x*t2.x + t2.y*t2.y + t2.z*t2.z + t2.w*t2.w;
    #pragma unroll
    for (int m = 1; m < 64; m <<= 1) { s += __shfl_xor(s, m, 64); s2 += __shfl_xor(s2, m, 64); }
    float mean = s * (1.0f / 768.0f);
    float var  = s2 * (1.0f / 768.0f) - mean * mean;
    float rs   = rsqrtf(var + 1e-5f);
    const f32x4* g4 = (const f32x4*)tw;
    const f32x4* b4 = (const f32x4*)tb;
    f32x4 g0 = g4[lane], g1 = g4[lane + 64], g2 = g4[lane + 128];
    f32x4 c0 = b4[lane], c1 = b4[lane + 64], c2 = b4[lane + 128];
    u16x4 o0 = { f2bf((t0.x - mean) * rs * g0.x + c0.x),
                 f2bf((t0.y - mean) * rs * g0.y + c0.y),
                 f2bf((t0.z - mean) * rs * g0.z + c0.z),
                 f2bf((t0.w - mean) * rs * g0.w + c0.w) };
    u16x4 o1 = { f2bf((t1.x - mean) * rs * g1.x + c1.x),
                 f2bf((t1.y - mean) * rs * g1.y + c1.y),
                 f2bf((t1.z - mean) * rs * g1.z + c1.z),
                 f2bf((t1.w - mean) * rs * g1.w + c1.w) };
    u16x4 o2 = { f2bf((t2.x - mean) * rs * g2.x + c2.x),
                 f2bf((t2.y - mean) * rs * g2.y + c2.y),
                 f2bf((t2.z - mean) * rs * g2.z + c2.z),
                 f2bf((t2.w - mean) * rs * g2.w + c2.w) };
    const int base = r * 1536, sw = (r & 7) << 4;
    *(u16x4*)(smem + ((base +        lane * 8) ^ sw)) = o0;
    *(u16x4*)(smem + ((base + 512  + lane * 8) ^ sw)) = o1;
    *(u16x4*)(smem + ((base + 1024 + lane * 8) ^ sw)) = o2;
  }
  __syncthreads();

  // ---------------- k GEMM: K=768 --------------------------------------------
  f32x4 ka[2][4] = {};
  {
    const unsigned short* bk = wbf + 262144 + wid * 49152 + lane * 8;
    for (int kk32 = 0; kk32 < 24; ++kk32) {
      short8 a[2];
      #pragma unroll
      for (int m = 0; m < 2; ++m) {
        int row = m * 16 + lr;
        int off = (row * 1536 + (kk32 * 32 + lkb) * 2) ^ ((row & 7) << 4);
        a[m] = *(const short8*)(smem + off);
      }
      #pragma unroll
      for (int n = 0; n < 4; ++n) {
        short8 b = *(const short8*)(bk + kk32 * 2048 + n * 512);
        #pragma unroll
        for (int m = 0; m < 2; ++m)
          ka[m][n] = __builtin_amdgcn_mfma_f32_16x16x32_bf16(a[m], b, ka[m][n], 0, 0, 0);
      }
    }
  }

  // ---------------- w gate: w[row,h] = (q·k)/8 over the wave's 64 channels ---
  float wgt[2][4];
  #pragma unroll
  for (int m = 0; m < 2; ++m) {
    #pragma unroll
    for (int r = 0; r < 4; ++r) {
      float p = 0.0f;
      #pragma unroll
      for (int n = 0; n < 4; ++n) p += qa[m][n][r] * ka[m][n][r];
      #pragma unroll
      for (int msk = 1; msk < 16; msk <<= 1) p += __shfl_xor(p, msk, 64);
      wgt[m][r] = p * 0.125f;   // 1/sqrt(64)
    }
  }

  // ---------------- y1 = (1-w) * q -------------------------------------------
  #pragma unroll
  for (int m = 0; m < 2; ++m) {
    #pragma unroll
    for (int r = 0; r < 4; ++r) {
      float f = 1.0f - wgt[m][r];
      long grow = row0 + m * 16 + lrow4 + r;
      #pragma unroll
      for (int n = 0; n < 4; ++n) {
        int ch = wid * 64 + n * 16 + lr;
        y1[grow * 512 + ch] = f * qa[m][n][r];
      }
    }
  }

  // ---------------- v GEMM: K=768, then y2 = w * v ----------------------------
  f32x4 va[2][4] = {};
  {
    const unsigned short* bv = wbf + 655360 + wid * 49152 + lane * 8;
    for (int kk32 = 0; kk32 < 24; ++kk32) {
      short8 a[2];
      #pragma unroll
      for (int m = 0; m < 2; ++m) {
        int row = m * 16 + lr;
        int off = (row * 1536 + (kk32 * 32 + lkb) * 2) ^ ((row & 7) << 4);
        a[m] = *(const short8*)(smem + off);
      }
      #pragma unroll
      for (int n = 0; n < 4; ++n) {
        short8 b = *(const short8*)(bv + kk32 * 2048 + n * 512);
        #pragma unroll
        for (int m = 0; m < 2; ++m)
          va[m][n] = __builtin_amdgcn_mfma_f32_16x16x32_bf16(a[m], b, va[m][n], 0, 0, 0);
      }
    }
  }
  #pragma unroll
  for (int m = 0; m < 2; ++m) {
    #pragma unroll
    for (int r = 0; r < 4; ++r) {
      float f = wgt[m][r];
      long grow = row0 + m * 16 + lrow4 + r;
      #pragma unroll
      for (int n = 0; n < 4; ++n) {
        int ch = wid * 64 + n * 16 + lr;
        y2[grow * 512 + ch] = f * va[m][n][r];
      }
    }
  }
}

extern "C" void kernel_launch(void* const* d_in, const int* in_sizes, int n_in,
                              void* d_out, int out_size, void* d_ws, size_t ws_size,
                              hipStream_t stream) {
  const float* x  = (const float*)d_in[0];
  const float* xf = (const float*)d_in[1];
  const float* nw = (const float*)d_in[2];
  const float* nb = (const float*)d_in[3];
  const float* tw = (const float*)d_in[4];
  const float* tb = (const float*)d_in[5];
  const float* wq = (const float*)d_in[6];
  const float* wk = (const float*)d_in[7];
  const float* wv = (const float*)d_in[8];
  unsigned short* wbf = (unsigned short*)d_ws;   // 2 MB bf16 packed weights

  cvt_weights<<<256, 256, 0, stream>>>(wq, wk, wv, wbf);
  fused_xattn<<<1024, NT, 0, stream>>>(x, xf, nw, nb, tw, tb, wbf, (float*)d_out);
}